// Round 4
// baseline (206.733 us; speedup 1.0000x reference)
//
#include <hip/hip_runtime.h>
#include <math.h>

#define MU_PRIOR   0.6447f
#define LOGDET_SA  4.767705615349743f   /* 3*ln(4.9) */
#define INV_SA     (1.0f/4.9f)

#define GRID    1024            /* 4 blocks/CU; grid-stride ~4 rows/thread */

#define W0 (1.0f / (0.0015f  * 0.0015f))
#define W1 (1.0f / (0.0012f  * 0.0012f))
#define W2 (1.0f / (0.0010f  * 0.0010f))
#define W3 (1.0f / (0.00086f * 0.00086f))
#define W4 (1.0f / (0.00057f * 0.00057f))

/* 4-byte-aligned vector loads (row offsets are 4B-aligned, not 16B) */
typedef float f4_t __attribute__((ext_vector_type(4)));
typedef f4_t uf4 __attribute__((aligned(4)));
typedef float f2_t __attribute__((ext_vector_type(2)));
typedef f2_t uf2 __attribute__((aligned(4)));

__device__ __forceinline__ float warp_reduce_f(float v) {
#pragma unroll
    for (int off = 32; off > 0; off >>= 1) v += __shfl_down(v, off, 64);
    return v;
}

__device__ __forceinline__ double warp_reduce_d(double v) {
#pragma unroll
    for (int off = 32; off > 0; off >>= 1) v += __shfl_down(v, off, 64);
    return v;
}

/* Row-per-thread streaming reduce (RMSNorm-style structure, m146 pattern:
 * 4.89 TB/s proven for this shape). No LDS in the loop, no wave_barrier, no
 * chunk-synchronous vmcnt drains: each thread's ~18 loads are independent
 * register dataflow, and #pragma unroll 2 lets the compiler hoist the next
 * row's loads above this row's compute. Occupancy is VGPR-bound only.
 * Rounds 0/3 (wave-chunk + LDS transpose) all pinned at 74 us / 2.7 TB/s
 * with VALUBusy <8%: the transpose machinery was the constraint, not HBM. */
__global__ __launch_bounds__(256) void loss_main(
    const float* __restrict__ pred, const float* __restrict__ yobs,
    const float* __restrict__ rrs,  const float* __restrict__ rrsp,
    const float* __restrict__ nanarr, const float* __restrict__ cov,
    const float* __restrict__ mu, double* __restrict__ partial, int rows)
{
    const int tid    = blockIdx.x * 256 + threadIdx.x;
    const int stride = (int)gridDim.x * 256;

    float acc = 0.0f;

#pragma unroll 2
    for (int r = tid; r < rows; r += stride) {
        const float* P = pred   + 9 * (size_t)r;
        const float* Y = yobs   + 9 * (size_t)r;
        const float* A = nanarr + 9 * (size_t)r;
        const float* C = cov    + 9 * (size_t)r;
        const float* R = rrs    + 5 * (size_t)r;
        const float* Q = rrsp   + 5 * (size_t)r;
        const float* M = mu     + 3 * (size_t)r;

        /* ---- issue all row loads (independent; 4B-aligned vectors) ---- */
        const uf4 p0 = *(const uf4*)P;       const uf4 p1 = *(const uf4*)(P + 4);
        const float p8 = P[8];
        const uf4 y0 = *(const uf4*)Y;       const uf4 y1 = *(const uf4*)(Y + 4);
        const float y8 = Y[8];
        const uf4 a0 = *(const uf4*)A;       const uf4 a1 = *(const uf4*)(A + 4);
        const float a8 = A[8];
        const uf4 c0 = *(const uf4*)C;       const uf4 c1 = *(const uf4*)(C + 4);
        const float c8 = C[8];
        const uf4 r0 = *(const uf4*)R;       const float r4 = R[4];
        const uf4 q0 = *(const uf4*)Q;       const float q4 = Q[4];
        const uf2 m0 = *(const uf2*)M;       const float m2 = M[2];

        /* ---- obs term: 10 * sum((p-y)^2) / len ---- */
        float dy2, len;
        {
            const float d0 = p0.x - y0.x, d1 = p0.y - y0.y;
            const float d2 = p0.z - y0.z, d3 = p0.w - y0.w;
            const float d4 = p1.x - y1.x, d5 = p1.y - y1.y;
            const float d6 = p1.z - y1.z, d7 = p1.w - y1.w;
            const float d8 = p8 - y8;
            dy2 = d0*d0 + d1*d1 + d2*d2 + d3*d3 + d4*d4
                + d5*d5 + d6*d6 + d7*d7 + d8*d8;
            len = ((a0.x == a0.x) ? 1.f : 0.f) + ((a0.y == a0.y) ? 1.f : 0.f)
                + ((a0.z == a0.z) ? 1.f : 0.f) + ((a0.w == a0.w) ? 1.f : 0.f)
                + ((a1.x == a1.x) ? 1.f : 0.f) + ((a1.y == a1.y) ? 1.f : 0.f)
                + ((a1.z == a1.z) ? 1.f : 0.f) + ((a1.w == a1.w) ? 1.f : 0.f)
                + ((a8   == a8  ) ? 1.f : 0.f);
        }
        acc += 10.0f * dy2 / len;

        /* ---- KL terms: logdet + trace of 3x3 cov row ---- */
        {
            const float tr  = c0.x + c1.x + c8;      /* c[0]+c[4]+c[8] */
            const float det = c0.x * (c1.x * c8   - c1.y * c1.w)
                            - c0.y * (c0.w * c8   - c1.y * c1.z)
                            + c0.z * (c0.w * c1.w - c1.x * c1.z);
            acc += 0.5f * (LOGDET_SA - __logf(det) + tr * INV_SA);
        }

        /* ---- rrs term: per-row weights, no rotation needed ---- */
        {
            const float d0 = r0.x - q0.x, d1 = r0.y - q0.y;
            const float d2 = r0.z - q0.z, d3 = r0.w - q0.w;
            const float d4 = r4 - q4;
            acc += (d0*d0*W0 + d1*d1*W1 + d2*d2*W2 + d3*d3*W3 + d4*d4*W4)
                   * 0.2f;
        }

        /* ---- mu term ---- */
        {
            const float d0 = m0.x - MU_PRIOR, d1 = m0.y - MU_PRIOR;
            const float d2 = m2 - MU_PRIOR;
            acc += (d0*d0 + d1*d1 + d2*d2) * (1.0f / 29.4f);
        }
    }

    /* ---- block reduction -> double partial ---- */
    acc = warp_reduce_f(acc);
    __shared__ float smem[4];
    const int lane = threadIdx.x & 63;
    const int wid  = threadIdx.x >> 6;
    if (lane == 0) smem[wid] = acc;
    __syncthreads();
    if (threadIdx.x == 0)
        partial[blockIdx.x] = (double)(smem[0] + smem[1] + smem[2] + smem[3]);
}

__global__ __launch_bounds__(256) void loss_final(
    const double* __restrict__ partial, int npartials,
    const float* __restrict__ params, int nparams,
    int rows, float* __restrict__ out)
{
    double accA = 0.0;   // per-row total (un-normalized)
    double accB = 0.0;   // l2 over parameters (un-normalized)

    for (int i = threadIdx.x; i < npartials; i += 256) accA += partial[i];
    for (int i = threadIdx.x; i < nparams; i += 256) {
        const float d = params[i] - 1.0f;
        accB += (double)(d * d);
    }

    double val = accA * (1.0 / (double)rows) + accB * (1.0 / (double)nparams);
    val = warp_reduce_d(val);
    __shared__ double sm[4];
    const int lane = threadIdx.x & 63;
    const int wid  = threadIdx.x >> 6;
    if (lane == 0) sm[wid] = val;
    __syncthreads();
    if (threadIdx.x == 0)
        out[0] = (float)(sm[0] + sm[1] + sm[2] + sm[3]);
}

extern "C" void kernel_launch(void* const* d_in, const int* in_sizes, int n_in,
                              void* d_out, int out_size, void* d_ws, size_t ws_size,
                              hipStream_t stream) {
    const float* pred   = (const float*)d_in[0];
    const float* yobs   = (const float*)d_in[1];
    const float* rrs    = (const float*)d_in[2];
    const float* rrsp   = (const float*)d_in[3];
    const float* nanarr = (const float*)d_in[4];
    const float* cov    = (const float*)d_in[5];
    const float* mu     = (const float*)d_in[6];
    const float* params = (const float*)d_in[7];
    float* out = (float*)d_out;

    const int rows = in_sizes[0] / 9;

    int grid = (rows + 255) / 256;
    if (grid > GRID) grid = GRID;
    if (grid < 1) grid = 1;

    double* partial = (double*)d_ws;   // `grid` doubles, all written every call

    loss_main<<<grid, 256, 0, stream>>>(pred, yobs, rrs, rrsp, nanarr,
                                        cov, mu, partial, rows);
    loss_final<<<1, 256, 0, stream>>>(partial, grid, params, in_sizes[7],
                                      rows, out);
}